// Round 1
// baseline (393.096 us; speedup 1.0000x reference)
//
#include <hip/hip_runtime.h>
#include <math.h>

#define NUM_CLASSES_ 100
#define C1_ 101
#define BQ_ 3200      // B*Q = 16*200
#define QDIM_ 200

// ---------------- init: zero accumulators, set target-class map to "empty" ----------------
__global__ void init_kernel(float* acc, int* tc) {
    int i = blockIdx.x * blockDim.x + threadIdx.x;
    if (i < 4) acc[i] = 0.0f;
    if (i < BQ_) tc[i] = -1;
}

// ---------------- scatter targets with last-write-wins (numpy semantics) ----------------
// pack (m << 8) | target ; larger m (later write) wins via atomicMax. target < 256.
__global__ void scatter_kernel(const int* __restrict__ targets,
                               const int* __restrict__ idx_b,
                               const int* __restrict__ idx_q,
                               int* tc, int M) {
    int m = blockIdx.x * blockDim.x + threadIdx.x;
    if (m < M) {
        int slot = idx_b[m] * QDIM_ + idx_q[m];
        atomicMax(&tc[slot], (m << 8) | targets[m]);
    }
}

// ---------------- weighted CE over 3200 rows x 101 classes, one wave per row ----------------
__global__ __launch_bounds__(256) void ce_kernel(const float* __restrict__ logits,
                                                 const int* __restrict__ tc,
                                                 const float* __restrict__ empty_w,
                                                 float* acc) {
    int lane = threadIdx.x & 63;
    int gw = (blockIdx.x * blockDim.x + threadIdx.x) >> 6;
    int nw = (gridDim.x * blockDim.x) >> 6;
    float lnum = 0.0f, lden = 0.0f;
    for (int row = gw; row < BQ_; row += nw) {
        const float* x = logits + (size_t)row * C1_;
        float x0 = x[lane];
        bool has2 = (lane < C1_ - 64);                 // lanes 0..36 hold a second element
        float x1 = has2 ? x[lane + 64] : -INFINITY;
        float m = fmaxf(x0, x1);
        #pragma unroll
        for (int off = 32; off; off >>= 1) m = fmaxf(m, __shfl_xor(m, off));
        float s = expf(x0 - m) + (has2 ? expf(x1 - m) : 0.0f);
        #pragma unroll
        for (int off = 32; off; off >>= 1) s += __shfl_xor(s, off);
        int packed = tc[row];
        int cls = (packed >= 0) ? (packed & 255) : NUM_CLASSES_;
        float xt = x[cls];                              // uniform addr -> broadcast load
        float nll = -(xt - m - logf(s));
        float w = empty_w[cls];
        lnum += w * nll;
        lden += w;
    }
    if (lane == 0) { atomicAdd(&acc[0], lnum); atomicAdd(&acc[1], lden); }
}

// ---------------- cluster cosine loss: one wave per pair ----------------
__global__ __launch_bounds__(256) void pair_kernel(const float* __restrict__ src,
                                                   const int* __restrict__ pairs,
                                                   const int* __restrict__ pos,
                                                   const float* __restrict__ pw,
                                                   float* acc, int P) {
    int lane = threadIdx.x & 63;
    int gw = (blockIdx.x * blockDim.x + threadIdx.x) >> 6;
    int nw = (gridDim.x * blockDim.x) >> 6;
    float num = 0.0f, den = 0.0f;
    for (int p = gw; p < P; p += nw) {
        int ia = pairs[2 * p];
        int ib = pairs[2 * p + 1];
        float dot = 0.0f, saa = 0.0f, sbb = 0.0f;
        if (lane < QDIM_ / 4) {   // 50 lanes x float4 = 200 floats = one row
            float4 a = *(reinterpret_cast<const float4*>(src + (size_t)ia * QDIM_) + lane);
            float4 b = *(reinterpret_cast<const float4*>(src + (size_t)ib * QDIM_) + lane);
            dot = a.x * b.x + a.y * b.y + a.z * b.z + a.w * b.w;
            saa = a.x * a.x + a.y * a.y + a.z * a.z + a.w * a.w;
            sbb = b.x * b.x + b.y * b.y + b.z * b.z + b.w * b.w;
        }
        #pragma unroll
        for (int off = 32; off; off >>= 1) {
            dot += __shfl_xor(dot, off);
            saa += __shfl_xor(saa, off);
            sbb += __shfl_xor(sbb, off);
        }
        float cosv = dot / (sqrtf(saa) * sqrtf(sbb) + 1e-8f);
        float per = pos[p] ? (1.0f - cosv) : fmaxf(cosv, 0.0f);   // nonzero test: works for int or f32 bools
        float w = fmaxf(pw[p], 0.1f);
        num += w * per;
        den += w;
    }
    // block reduce -> 2 atomics per block
    __shared__ float snum[4], sden[4];
    int wib = threadIdx.x >> 6;
    if (lane == 0) { snum[wib] = num; sden[wib] = den; }
    __syncthreads();
    if (threadIdx.x == 0) {
        float n = snum[0] + snum[1] + snum[2] + snum[3];
        float d = sden[0] + sden[1] + sden[2] + sden[3];
        atomicAdd(&acc[2], n);
        atomicAdd(&acc[3], d);
    }
}

// ---------------- combine ----------------
__global__ void final_kernel(const float* __restrict__ acc, float* out) {
    if (threadIdx.x == 0 && blockIdx.x == 0)
        out[0] = acc[0] / acc[1] + acc[2] / acc[3];
}

extern "C" void kernel_launch(void* const* d_in, const int* in_sizes, int n_in,
                              void* d_out, int out_size, void* d_ws, size_t ws_size,
                              hipStream_t stream) {
    const float* pred_logits = (const float*)d_in[0];
    const int*   targets     = (const int*)d_in[1];
    const int*   idx_b       = (const int*)d_in[2];
    const int*   idx_q       = (const int*)d_in[3];
    const float* src         = (const float*)d_in[4];
    const int*   pairs       = (const int*)d_in[5];
    const int*   pair_pos    = (const int*)d_in[6];
    const float* pair_w      = (const float*)d_in[7];
    const float* empty_w     = (const float*)d_in[8];
    float* out = (float*)d_out;

    float* acc = (float*)d_ws;                 // 4 floats: {ce_num, ce_den, cl_num, cl_den}
    int*   tc  = (int*)((char*)d_ws + 16);     // 3200 ints: packed target-class map

    int M = in_sizes[1];
    int P = in_sizes[7];

    init_kernel<<<(BQ_ + 255) / 256, 256, 0, stream>>>(acc, tc);
    scatter_kernel<<<(M + 255) / 256, 256, 0, stream>>>(targets, idx_b, idx_q, tc, M);
    ce_kernel<<<50, 256, 0, stream>>>(pred_logits, tc, empty_w, acc);
    pair_kernel<<<2048, 256, 0, stream>>>(src, pairs, pair_pos, pair_w, acc, P);
    final_kernel<<<1, 64, 0, stream>>>(acc, out);
}